// Round 7
// baseline (250.933 us; speedup 1.0000x reference)
//
#include <hip/hip_runtime.h>
#include <hip/hip_bf16.h>

typedef unsigned short u16;
typedef unsigned int   u32;
typedef __attribute__((ext_vector_type(8))) __bf16 bf16x8;
typedef __attribute__((ext_vector_type(2))) __bf16 bf16x2;
typedef __attribute__((ext_vector_type(8))) u16    ushort8v;
typedef __attribute__((ext_vector_type(2))) float  f32x2;
typedef __attribute__((ext_vector_type(4))) float  floatx4;

#define EMBED 1024
#define SEQ   2048
#define BATCH 4
#define NH    16
#define DKH   64
#define BHN   (BATCH*NH)              // 64
#define ZSTRIDE ((size_t)BHN*SEQ*DKH) // elements per Q/K/V plane

// ---- fp32 -> bf16 RTNE ----
__device__ __forceinline__ u16 f2bf(float f){
  union { float f; unsigned u; } v; v.f = f;
  unsigned r = (v.u + 0x7FFFu + ((v.u >> 16) & 1u)) >> 16;
  return (u16)r;
}
// packed pair via v_cvt_pk_bf16_f32
__device__ __forceinline__ u32 pk2(float a, float b){
  f32x2 v = {a, b};
  return __builtin_bit_cast(u32, __builtin_convertvector(v, bf16x2));
}

__device__ __forceinline__ bf16x8 ld_frag(const u16* p){
  return __builtin_bit_cast(bf16x8, *(const ushort8v*)p);
}

__device__ __forceinline__ floatx4 mfma16(bf16x8 a, bf16x8 b, floatx4 c){
  return __builtin_amdgcn_mfma_f32_16x16x32_bf16(a, b, c, 0, 0, 0);
}

// async global->LDS, 16B per lane; LDS dst must be uniform_base + lane*16
__device__ __forceinline__ void gl_lds16(const u16* g, u16* l){
  __builtin_amdgcn_global_load_lds((const __attribute__((address_space(1))) void*)g,
                                   (__attribute__((address_space(3))) void*)l,
                                   16, 0, 0);
}

// =================== fused cast kernel ===================
__global__ __launch_bounds__(256) void cvt_all(const float* __restrict__ x,
    const float* __restrict__ wq, const float* __restrict__ wk,
    const float* __restrict__ wv, const float* __restrict__ wo,
    u16* __restrict__ Xb, u16* __restrict__ Wqb, u16* __restrict__ Wkb,
    u16* __restrict__ Wvb, u16* __restrict__ Wob){
  int b = blockIdx.x;
  const float* src; u16* dst; int i;
  if (b < 8192){ src = x; dst = Xb; i = b*256 + threadIdx.x; }
  else {
    int k = (b - 8192) >> 10, r = (b - 8192) & 1023;
    src = (k==0) ? wq : (k==1) ? wk : (k==2) ? wv : wo;
    dst = (k==0) ? Wqb : (k==1) ? Wkb : (k==2) ? Wvb : Wob;
    i = r*256 + threadIdx.x;
  }
  float4 v = ((const float4*)src)[i];
  ushort4 o;
  o.x = f2bf(v.x); o.y = f2bf(v.y); o.z = f2bf(v.z); o.w = f2bf(v.w);
  ((ushort4*)dst)[i] = o;
}

// ============== fused QKV projection (R3-v1, measured 68 us) ===================
// grid (64, 8): x = m-tile (128 rows), y = n-tile (128 cols). Q,K,V share the
// A operand -> stage X ONCE per kt, 3 B tiles, 48 MFMA/wave/kt per barrier.
// R4 lesson: work-per-barrier dominates waves/SIMD at K=1024 — keep the big
// acc[3][4][4] tile. R5 lesson: f32-X staging fold regressed (+12 us).
// LDS = 64 KB -> 2 blocks/CU, 512 blocks = full residency, zero tail.
// z=0: Q (scaled), z=1: K — layout [bh][s][d]; z=2: V — layout [bh][d][s].
#define QSCALE 0.1803368801111204f   // 0.125 * log2(e)
__global__ __launch_bounds__(256, 2) void gemm_qkv(const u16* __restrict__ X,
    const u16* __restrict__ Wq, const u16* __restrict__ Wk, const u16* __restrict__ Wv,
    u16* __restrict__ QKV){
  __shared__ __attribute__((aligned(16))) u16 As[2*128*32];      // 16 KB
  __shared__ __attribute__((aligned(16))) u16 Bs[3][2*128*32];   // 48 KB

  const int tid = threadIdx.x, lane = tid & 63, w = tid >> 6;
  const int lm = lane & 15, quad = lane >> 4;
  const int wm = (w & 1) * 64, wn = (w >> 1) * 64;
  const int m0 = blockIdx.x * 128, n0 = blockIdx.y * 128;
  const int row0 = tid >> 2, kc = tid & 3;

  const u16* A0 = X  + (size_t)(m0 + row0)*EMBED + kc*8;   // +64*EMBED for r=1
  const u16* B0[3] = {
    Wq + (size_t)(n0 + row0)*EMBED + kc*8,
    Wk + (size_t)(n0 + row0)*EMBED + kc*8,
    Wv + (size_t)(n0 + row0)*EMBED + kc*8 };

  floatx4 acc[3][4][4];
  #pragma unroll
  for (int z = 0; z < 3; ++z)
    #pragma unroll
    for (int mi = 0; mi < 4; ++mi)
      #pragma unroll
      for (int ni = 0; ni < 4; ++ni)
        acc[z][mi][ni] = (floatx4){0.f, 0.f, 0.f, 0.f};

  // prologue: stage kt=0 into buffer 0
  gl_lds16(A0,            As + tid*8);
  gl_lds16(A0 + 64*EMBED, As + (256 + tid)*8);
  #pragma unroll
  for (int z = 0; z < 3; ++z){
    gl_lds16(B0[z],            Bs[z] + tid*8);
    gl_lds16(B0[z] + 64*EMBED, Bs[z] + (256 + tid)*8);
  }

  for (int kt = 0; kt < EMBED/32; ++kt){
    const int cur = kt & 1;
    // one barrier per kt: drains vmcnt (buf[cur] DMA done) + all waves done
    // reading buf[cur^1] last iter -> safe to overwrite below.
    __syncthreads();
    if (kt + 1 < EMBED/32){
      const int k0 = (kt + 1) * 32;
      gl_lds16(A0 + k0,            As + (cur^1)*4096 + tid*8);
      gl_lds16(A0 + 64*EMBED + k0, As + (cur^1)*4096 + (256 + tid)*8);
      #pragma unroll
      for (int z = 0; z < 3; ++z){
        gl_lds16(B0[z] + k0,            Bs[z] + (cur^1)*4096 + tid*8);
        gl_lds16(B0[z] + 64*EMBED + k0, Bs[z] + (cur^1)*4096 + (256 + tid)*8);
      }
    }
    const u16* Ac = As + cur*4096;
    bf16x8 af[4];
    #pragma unroll
    for (int mi = 0; mi < 4; ++mi)
      af[mi] = ld_frag(&Ac[(wm + mi*16 + lm)*32 + quad*8]);
    #pragma unroll
    for (int z = 0; z < 3; ++z){
      const u16* Bc = Bs[z] + cur*4096;
      bf16x8 bfz[4];
      #pragma unroll
      for (int ni = 0; ni < 4; ++ni)
        bfz[ni] = ld_frag(&Bc[(wn + ni*16 + lm)*32 + quad*8]);
      #pragma unroll
      for (int mi = 0; mi < 4; ++mi)
        #pragma unroll
        for (int ni = 0; ni < 4; ++ni)
          acc[z][mi][ni] = mfma16(af[mi], bfz[ni], acc[z][mi][ni]);
    }
  }

  // ---- epilogues: direct stores ----
  // z=0 (Q, scaled) and z=1 (K): [bh][s][d]
  #pragma unroll
  for (int z = 0; z < 2; ++z){
    const float scale = (z == 0) ? QSCALE : 1.0f;
    u16* outz = QKV + (size_t)z * ZSTRIDE;
    #pragma unroll
    for (int mi = 0; mi < 4; ++mi)
      #pragma unroll
      for (int ni = 0; ni < 4; ++ni)
        #pragma unroll
        for (int r = 0; r < 4; ++r){
          int m = m0 + wm + mi*16 + quad*4 + r;
          int n = n0 + wn + ni*16 + lm;
          int b = m >> 11, s = m & 2047, h = n >> 6, d = n & 63;
          outz[(((size_t)(b*NH + h))*SEQ + s)*DKH + d] = f2bf(acc[z][mi][ni][r] * scale);
        }
  }
  // z=2 (V): [bh][d][s], 4 consecutive s per thread -> uint2 store
  {
    u16* outz = QKV + (size_t)2 * ZSTRIDE;
    #pragma unroll
    for (int mi = 0; mi < 4; ++mi)
      #pragma unroll
      for (int ni = 0; ni < 4; ++ni){
        int mbase = m0 + wm + mi*16 + quad*4;
        int n = n0 + wn + ni*16 + lm;
        int b = mbase >> 11, sb = mbase & 2047;
        int h = n >> 6, d = n & 63;
        u16* dst = outz + (((size_t)(b*NH + h))*DKH + d)*SEQ + sb;
        uint2 pv;
        pv.x = pk2(acc[2][mi][ni][0], acc[2][mi][ni][1]);
        pv.y = pk2(acc[2][mi][ni][2], acc[2][mi][ni][3]);
        *reinterpret_cast<uint2*>(dst) = pv;
      }
  }
}

// Final: out = Attn * Wo^T, fp32 out [b*s][e]. grid (64, 8). BK=64 (R6: -4 us),
// source-side XOR swizzle on staging, same XOR on read.
__global__ __launch_bounds__(256) void gemm_out(const u16* __restrict__ A,
    const u16* __restrict__ W, float* __restrict__ C){
  __shared__ __attribute__((aligned(16))) u16 As[2*128*64];   // 32 KB
  __shared__ __attribute__((aligned(16))) u16 Bs[2*128*64];   // 32 KB
  const int tid = threadIdx.x, lane = tid & 63, w = tid >> 6;
  const int lm = lane & 15, quad = lane >> 4;
  const int wm = (w & 1) * 64, wn = (w >> 1) * 64;
  const int m0 = blockIdx.x * 128, n0 = blockIdx.y * 128;

  const int srow = tid >> 3;
  const int ssw  = ((tid & 7) ^ (srow & 7)) * 8;   // u16 col offset
  const u16* Ab = A + (size_t)(m0 + srow)*EMBED + ssw;
  const u16* Bb = W + (size_t)(n0 + srow)*EMBED + ssw;

  floatx4 acc[4][4];
  #pragma unroll
  for (int mi = 0; mi < 4; ++mi)
    #pragma unroll
    for (int ni = 0; ni < 4; ++ni)
      acc[mi][ni] = (floatx4){0.f, 0.f, 0.f, 0.f};

  #pragma unroll
  for (int j = 0; j < 4; ++j){
    gl_lds16(Ab + (size_t)j*32*EMBED, As + (j*256 + tid)*8);
    gl_lds16(Bb + (size_t)j*32*EMBED, Bs + (j*256 + tid)*8);
  }

  for (int kt = 0; kt < EMBED/64; ++kt){
    const int cur = kt & 1;
    __syncthreads();
    if (kt + 1 < EMBED/64){
      const int k0 = (kt + 1) * 64;
      #pragma unroll
      for (int j = 0; j < 4; ++j){
        gl_lds16(Ab + (size_t)j*32*EMBED + k0, As + (cur^1)*8192 + (j*256 + tid)*8);
        gl_lds16(Bb + (size_t)j*32*EMBED + k0, Bs + (cur^1)*8192 + (j*256 + tid)*8);
      }
    }
    const u16* Ac = As + cur*8192;
    const u16* Bc = Bs + cur*8192;
    #pragma unroll
    for (int kh = 0; kh < 2; ++kh){
      const int us = ((kh*4 + quad) ^ (lm & 7)) * 8;
      bf16x8 af[4], bf[4];
      #pragma unroll
      for (int mi = 0; mi < 4; ++mi)
        af[mi] = ld_frag(&Ac[(wm + mi*16 + lm)*64 + us]);
      #pragma unroll
      for (int ni = 0; ni < 4; ++ni)
        bf[ni] = ld_frag(&Bc[(wn + ni*16 + lm)*64 + us]);
      #pragma unroll
      for (int mi = 0; mi < 4; ++mi)
        #pragma unroll
        for (int ni = 0; ni < 4; ++ni)
          acc[mi][ni] = mfma16(af[mi], bf[ni], acc[mi][ni]);
    }
  }

  #pragma unroll
  for (int mi = 0; mi < 4; ++mi)
    #pragma unroll
    for (int ni = 0; ni < 4; ++ni)
      #pragma unroll
      for (int r = 0; r < 4; ++r){
        int m = m0 + wm + mi*16 + quad*4 + r;
        int n = n0 + wn + ni*16 + lm;
        C[(size_t)m*EMBED + n] = acc[mi][ni][r];
      }
}

// =================== fused attention (P stays in registers) ===================
// grid (64, 16): x = bh, y = q-block of 128 rows. 4 waves x 32 q (2 q-tiles).
// Keys chunked by 64, K/V double-buffered DMA, single barrier per kt.
// R6 diagnosis: MfmaUtil 38.6 + VALUBusy 45.4 + LDS ~13 = 97% — pipes fully
// SERIALIZE. Cause: per-(tile,qt) 2-MFMA -> dependent 4-exp2 micro-chunks keep
// all barrier-locked waves in the same burst phase. Fix (this round): widen
// the per-kt DAG — order QK(t0) QK(t1) exp(t0) QK(t2) exp(t1) QK(t3) exp(t2)
// PV(u0) exp(t3) PV(u1), so every trans burst neighbors an independent MFMA
// burst in one basic block. setprio pairs REMOVED (neutral per R3, and they
// fence scheduler motion). Accumulator op order unchanged -> bit-identical.
#define KSS 520
__global__ __launch_bounds__(256, 4) void attn_kernel(const u16* __restrict__ QKV,
                                                      u16* __restrict__ Out){
  __shared__ __attribute__((aligned(16))) u16 Ks[2][8*KSS];   // 16.6 KB
  __shared__ __attribute__((aligned(16))) u16 Vs[2][64*64];   // 16.4 KB

  const int tid = threadIdx.x, lane = tid & 63, w = tid >> 6;
  const int lm = lane & 15, quad = lane >> 4;
  const int bh = blockIdx.x;
  const int q0 = blockIdx.y * 128;
  const u16* Qh = QKV + (size_t)bh * SEQ * DKH;
  const u16* Kh = QKV + ZSTRIDE + (size_t)bh * SEQ * DKH;
  const u16* Vh = QKV + 2*ZSTRIDE + (size_t)bh * DKH * SEQ;  // [d][s] plain

  const int sK = tid & 63, cK = tid >> 6;
  const int dV = tid >> 3, gV = tid & 7;
  const size_t vsrc0 = (size_t)dV * SEQ + ((gV ^ (dV & 7)) * 8);
  const size_t vsrc1 = vsrc0 + (size_t)32 * SEQ;

  bf16x8 qf[2][2];
  #pragma unroll
  for (int qt = 0; qt < 2; ++qt)
    #pragma unroll
    for (int st = 0; st < 2; ++st)
      qf[qt][st] = ld_frag(Qh + (size_t)(q0 + w*32 + qt*16 + lm)*DKH + st*32 + quad*8);

  const uint4 ONESW = {0x3F803F80u, 0x3F803F80u, 0x3F803F80u, 0x3F803F80u};
  const bf16x8 ones8 = __builtin_bit_cast(bf16x8, ONESW);    // bf16 1.0 x8

  floatx4 o[2][4], lac[2];
  #pragma unroll
  for (int qt = 0; qt < 2; ++qt){
    lac[qt] = (floatx4){0.f, 0.f, 0.f, 0.f};
    #pragma unroll
    for (int dt = 0; dt < 4; ++dt) o[qt][dt] = (floatx4){0.f, 0.f, 0.f, 0.f};
  }

  gl_lds16(Kh + (size_t)sK*DKH + cK*8,     Ks[0] + cK*KSS + sK*8);
  gl_lds16(Kh + (size_t)sK*DKH + (cK+4)*8, Ks[0] + (cK+4)*KSS + sK*8);
  gl_lds16(Vh + vsrc0,                     Vs[0] + tid*8);
  gl_lds16(Vh + vsrc1,                     Vs[0] + 2048 + tid*8);

  for (int kt = 0; kt < SEQ/64; ++kt){
    const int cur = kt & 1;
    __syncthreads();
    if (kt + 1 < SEQ/64){
      const int nk0 = (kt + 1) * 64;
      gl_lds16(Kh + (size_t)(nk0 + sK)*DKH + cK*8,     Ks[cur^1] + cK*KSS + sK*8);
      gl_lds16(Kh + (size_t)(nk0 + sK)*DKH + (cK+4)*8, Ks[cur^1] + (cK+4)*KSS + sK*8);
      gl_lds16(Vh + vsrc0 + nk0,                       Vs[cur^1] + tid*8);
      gl_lds16(Vh + vsrc1 + nk0,                       Vs[cur^1] + 2048 + tid*8);
    }
    const u16* Kc = Ks[cur];
    const u16* Vc = Vs[cur];

    // ---- widest-DAG schedule for this kt ----
    auto QK = [&](int t, floatx4& s0, floatx4& s1){
      bf16x8 kf0 = ld_frag(&Kc[quad*KSS     + (t*16 + lm)*8]);
      bf16x8 kf1 = ld_frag(&Kc[(quad+4)*KSS + (t*16 + lm)*8]);
      floatx4 a = (floatx4){0.f,0.f,0.f,0.f};
      a = mfma16(kf0, qf[0][0], a);
      a = mfma16(kf1, qf[0][1], a);
      s0 = a;
      floatx4 b = (floatx4){0.f,0.f,0.f,0.f};
      b = mfma16(kf0, qf[1][0], b);
      b = mfma16(kf1, qf[1][1], b);
      s1 = b;
    };
    auto EXP = [&](const floatx4& s) -> uint2 {
      uint2 p;
      p.x = pk2(__builtin_amdgcn_exp2f(s[0]), __builtin_amdgcn_exp2f(s[1]));
      p.y = pk2(__builtin_amdgcn_exp2f(s[2]), __builtin_amdgcn_exp2f(s[3]));
      return p;
    };

    floatx4 sa0, sa1, sb0, sb1, sc0, sc1, sd0, sd1;
    uint2 e00, e01, e10, e11, e20, e21, e30, e31;   // e{tile}{qt}

    QK(0, sa0, sa1);                 // 4 MFMA
    QK(1, sb0, sb1);                 // 4 MFMA
    e00 = EXP(sa0); e01 = EXP(sa1);  // 8 exp2  (independent of QK(1)/QK(2))
    QK(2, sc0, sc1);                 // 4 MFMA
    e10 = EXP(sb0); e11 = EXP(sb1);  // 8 exp2
    QK(3, sd0, sd1);                 // 4 MFMA
    e20 = EXP(sc0); e21 = EXP(sc1);  // 8 exp2

    // PV u=0 (tiles 0,1)
    {
      uint4 pp0 = {e00.x, e00.y, e10.x, e10.y};
      uint4 pp1 = {e01.x, e01.y, e11.x, e11.y};
      bf16x8 pf0 = __builtin_bit_cast(bf16x8, pp0);
      bf16x8 pf1 = __builtin_bit_cast(bf16x8, pp1);
      lac[0] = mfma16(pf0, ones8, lac[0]);
      lac[1] = mfma16(pf1, ones8, lac[1]);
      const int cg0 = (((0 + (quad >> 1)) ^ (lm & 7)) * 8) + (quad & 1) * 4;
      const int cg1 = (((2 + (quad >> 1)) ^ (lm & 7)) * 8) + (quad & 1) * 4;
      #pragma unroll
      for (int dt = 0; dt < 4; ++dt){
        uint2 vlo = *(const uint2*)(Vc + (dt*16 + lm)*64 + cg0);
        uint2 vhi = *(const uint2*)(Vc + (dt*16 + lm)*64 + cg1);
        uint4 vv = {vlo.x, vlo.y, vhi.x, vhi.y};
        bf16x8 vb = __builtin_bit_cast(bf16x8, vv);
        o[0][dt] = mfma16(pf0, vb, o[0][dt]);
        o[1][dt] = mfma16(pf1, vb, o[1][dt]);
      }
    }

    e30 = EXP(sd0); e31 = EXP(sd1);  // 8 exp2 (independent of PV u=0 above)

    // PV u=1 (tiles 2,3)
    {
      uint4 pp0 = {e20.x, e20.y, e30.x, e30.y};
      uint4 pp1 = {e21.x, e21.y, e31.x, e31.y};
      bf16x8 pf0 = __builtin_bit_cast(bf16x8, pp0);
      bf16x8 pf1 = __builtin_bit_cast(bf16x8, pp1);
      lac[0] = mfma16(pf0, ones8, lac[0]);
      lac[1] = mfma16(pf1, ones8, lac[1]);
      const int cg0 = (((4 + (quad >> 1)) ^ (lm & 7)) * 8) + (quad & 1) * 4;
      const int cg1 = (((6 + (quad >> 1)) ^ (lm & 7)) * 8) + (quad & 1) * 4;
      #pragma unroll
      for (int dt = 0; dt < 4; ++dt){
        uint2 vlo = *(const uint2*)(Vc + (dt*16 + lm)*64 + cg0);
        uint2 vhi = *(const uint2*)(Vc + (dt*16 + lm)*64 + cg1);
        uint4 vv = {vlo.x, vlo.y, vhi.x, vhi.y};
        bf16x8 vb = __builtin_bit_cast(bf16x8, vv);
        o[0][dt] = mfma16(pf0, vb, o[0][dt]);
        o[1][dt] = mfma16(pf1, vb, o[1][dt]);
      }
    }
  }

  const int bI = bh >> 4, h = bh & 15;
  #pragma unroll
  for (int qt = 0; qt < 2; ++qt){
    floatx4 inv;
    #pragma unroll
    for (int r = 0; r < 4; ++r) inv[r] = __builtin_amdgcn_rcpf(lac[qt][r]);
    #pragma unroll
    for (int dt = 0; dt < 4; ++dt)
      #pragma unroll
      for (int r = 0; r < 4; ++r){
        int s = q0 + w*32 + qt*16 + quad*4 + r;
        Out[((size_t)(bI*SEQ + s))*EMBED + h*DKH + dt*16 + lm] = f2bf(o[qt][dt][r] * inv[r]);
      }
  }
}

// =================== launch ===================
extern "C" void kernel_launch(void* const* d_in, const int* in_sizes, int n_in,
                              void* d_out, int out_size, void* d_ws, size_t ws_size,
                              hipStream_t stream){
  const float* x  = (const float*)d_in[0];
  const float* Wq = (const float*)d_in[1];
  const float* Wk = (const float*)d_in[2];
  const float* Wv = (const float*)d_in[3];
  const float* Wo = (const float*)d_in[4];
  float* out = (float*)d_out;

  char* ws = (char*)d_ws;
  u16* Xb  = (u16*)ws;                          // 16 MB
  u16* Wqb = (u16*)(ws + (size_t)16777216);     // 4 x 2 MB
  u16* Wkb = Wqb + 1048576;
  u16* Wvb = Wkb + 1048576;
  u16* Wob = Wvb + 1048576;
  u16* QKV = (u16*)(ws + (size_t)25165824);     // 3 x 16.78 MB
  u16* At  = (u16*)(ws + (size_t)75497472);     // 16 MB

  cvt_all<<<12288, 256, 0, stream>>>(x, Wq, Wk, Wv, Wo, Xb, Wqb, Wkb, Wvb, Wob);
  gemm_qkv<<<dim3(64, 8), 256, 0, stream>>>(Xb, Wqb, Wkb, Wvb, QKV);
  attn_kernel<<<dim3(64, 16), 256, 0, stream>>>(QKV, At);
  gemm_out<<<dim3(64, 8), 256, 0, stream>>>(At, Wob, out);
}

// Round 8
// 247.494 us; speedup vs baseline: 1.0139x; 1.0139x over previous
//
#include <hip/hip_runtime.h>
#include <hip/hip_bf16.h>

typedef unsigned short u16;
typedef unsigned int   u32;
typedef __attribute__((ext_vector_type(8))) __bf16 bf16x8;
typedef __attribute__((ext_vector_type(2))) __bf16 bf16x2;
typedef __attribute__((ext_vector_type(8))) u16    ushort8v;
typedef __attribute__((ext_vector_type(2))) float  f32x2;
typedef __attribute__((ext_vector_type(4))) float  floatx4;

#define EMBED 1024
#define SEQ   2048
#define BATCH 4
#define NH    16
#define DKH   64
#define BHN   (BATCH*NH)              // 64
#define ZSTRIDE ((size_t)BHN*SEQ*DKH) // elements per Q/K/V plane

// ---- fp32 -> bf16 RTNE ----
__device__ __forceinline__ u16 f2bf(float f){
  union { float f; unsigned u; } v; v.f = f;
  unsigned r = (v.u + 0x7FFFu + ((v.u >> 16) & 1u)) >> 16;
  return (u16)r;
}
// packed pair via v_cvt_pk_bf16_f32
__device__ __forceinline__ u32 pk2(float a, float b){
  f32x2 v = {a, b};
  return __builtin_bit_cast(u32, __builtin_convertvector(v, bf16x2));
}

__device__ __forceinline__ bf16x8 ld_frag(const u16* p){
  return __builtin_bit_cast(bf16x8, *(const ushort8v*)p);
}

__device__ __forceinline__ floatx4 mfma16(bf16x8 a, bf16x8 b, floatx4 c){
  return __builtin_amdgcn_mfma_f32_16x16x32_bf16(a, b, c, 0, 0, 0);
}

// async global->LDS, 16B per lane; LDS dst must be uniform_base + lane*16
__device__ __forceinline__ void gl_lds16(const u16* g, u16* l){
  __builtin_amdgcn_global_load_lds((const __attribute__((address_space(1))) void*)g,
                                   (__attribute__((address_space(3))) void*)l,
                                   16, 0, 0);
}

// T4 counted-vmcnt barrier discipline (m201/m218 pattern):
//   B1 (all waves done READING buf[cur^1]) -> issue prefetch into cur^1 ->
//   s_waitcnt vmcnt(N) (buf[cur] landed, prefetch stays IN FLIGHT) ->
//   B2 (every wave's counted wait passed => buf[cur] landed block-wide) ->
//   compute. Replaces __syncthreads' full vmcnt(0) drain (the ~20% stall).
#define CFENCE asm volatile("" ::: "memory")

// =================== fused cast kernel ===================
__global__ __launch_bounds__(256) void cvt_all(const float* __restrict__ x,
    const float* __restrict__ wq, const float* __restrict__ wk,
    const float* __restrict__ wv, const float* __restrict__ wo,
    u16* __restrict__ Xb, u16* __restrict__ Wqb, u16* __restrict__ Wkb,
    u16* __restrict__ Wvb, u16* __restrict__ Wob){
  int b = blockIdx.x;
  const float* src; u16* dst; int i;
  if (b < 8192){ src = x; dst = Xb; i = b*256 + threadIdx.x; }
  else {
    int k = (b - 8192) >> 10, r = (b - 8192) & 1023;
    src = (k==0) ? wq : (k==1) ? wk : (k==2) ? wv : wo;
    dst = (k==0) ? Wqb : (k==1) ? Wkb : (k==2) ? Wvb : Wob;
    i = r*256 + threadIdx.x;
  }
  float4 v = ((const float4*)src)[i];
  ushort4 o;
  o.x = f2bf(v.x); o.y = f2bf(v.y); o.z = f2bf(v.z); o.w = f2bf(v.w);
  ((ushort4*)dst)[i] = o;
}

// ============== fused QKV projection (R3-v1 + counted vmcnt) ===================
// grid (64, 8): x = m-tile (128 rows), y = n-tile (128 cols). Q,K,V share the
// A operand -> stage X ONCE per kt, 3 B tiles, 48 MFMA/wave/kt per barrier.
// LDS = 64 KB -> 2 blocks/CU. 8 DMA/thread/kt -> steady vmcnt(8).
#define QSCALE 0.1803368801111204f   // 0.125 * log2(e)
__global__ __launch_bounds__(256, 2) void gemm_qkv(const u16* __restrict__ X,
    const u16* __restrict__ Wq, const u16* __restrict__ Wk, const u16* __restrict__ Wv,
    u16* __restrict__ QKV){
  __shared__ __attribute__((aligned(16))) u16 As[2*128*32];      // 16 KB
  __shared__ __attribute__((aligned(16))) u16 Bs[3][2*128*32];   // 48 KB

  const int tid = threadIdx.x, lane = tid & 63, w = tid >> 6;
  const int lm = lane & 15, quad = lane >> 4;
  const int wm = (w & 1) * 64, wn = (w >> 1) * 64;
  const int m0 = blockIdx.x * 128, n0 = blockIdx.y * 128;
  const int row0 = tid >> 2, kc = tid & 3;

  const u16* A0 = X  + (size_t)(m0 + row0)*EMBED + kc*8;   // +64*EMBED for r=1
  const u16* B0[3] = {
    Wq + (size_t)(n0 + row0)*EMBED + kc*8,
    Wk + (size_t)(n0 + row0)*EMBED + kc*8,
    Wv + (size_t)(n0 + row0)*EMBED + kc*8 };

  floatx4 acc[3][4][4];
  #pragma unroll
  for (int z = 0; z < 3; ++z)
    #pragma unroll
    for (int mi = 0; mi < 4; ++mi)
      #pragma unroll
      for (int ni = 0; ni < 4; ++ni)
        acc[z][mi][ni] = (floatx4){0.f, 0.f, 0.f, 0.f};

  // prologue: stage kt=0 into buffer 0 (8 DMAs in flight)
  gl_lds16(A0,            As + tid*8);
  gl_lds16(A0 + 64*EMBED, As + (256 + tid)*8);
  #pragma unroll
  for (int z = 0; z < 3; ++z){
    gl_lds16(B0[z],            Bs[z] + tid*8);
    gl_lds16(B0[z] + 64*EMBED, Bs[z] + (256 + tid)*8);
  }

  for (int kt = 0; kt < EMBED/32; ++kt){
    const int cur = kt & 1;
    __builtin_amdgcn_s_barrier();          // B1: all waves done reading cur^1
    CFENCE;
    if (kt + 1 < EMBED/32){
      const int k0 = (kt + 1) * 32;
      gl_lds16(A0 + k0,            As + (cur^1)*4096 + tid*8);
      gl_lds16(A0 + 64*EMBED + k0, As + (cur^1)*4096 + (256 + tid)*8);
      #pragma unroll
      for (int z = 0; z < 3; ++z){
        gl_lds16(B0[z] + k0,            Bs[z] + (cur^1)*4096 + tid*8);
        gl_lds16(B0[z] + 64*EMBED + k0, Bs[z] + (cur^1)*4096 + (256 + tid)*8);
      }
      asm volatile("s_waitcnt vmcnt(8)" ::: "memory");   // cur landed, 8 in flight
    } else {
      asm volatile("s_waitcnt vmcnt(0)" ::: "memory");
    }
    __builtin_amdgcn_s_barrier();          // B2: cur landed block-wide
    CFENCE;
    const u16* Ac = As + cur*4096;
    bf16x8 af[4];
    #pragma unroll
    for (int mi = 0; mi < 4; ++mi)
      af[mi] = ld_frag(&Ac[(wm + mi*16 + lm)*32 + quad*8]);
    #pragma unroll
    for (int z = 0; z < 3; ++z){
      const u16* Bc = Bs[z] + cur*4096;
      bf16x8 bfz[4];
      #pragma unroll
      for (int ni = 0; ni < 4; ++ni)
        bfz[ni] = ld_frag(&Bc[(wn + ni*16 + lm)*32 + quad*8]);
      #pragma unroll
      for (int mi = 0; mi < 4; ++mi)
        #pragma unroll
        for (int ni = 0; ni < 4; ++ni)
          acc[z][mi][ni] = mfma16(af[mi], bfz[ni], acc[z][mi][ni]);
    }
  }

  // ---- epilogues: direct stores ----
  // z=0 (Q, scaled) and z=1 (K): [bh][s][d]
  #pragma unroll
  for (int z = 0; z < 2; ++z){
    const float scale = (z == 0) ? QSCALE : 1.0f;
    u16* outz = QKV + (size_t)z * ZSTRIDE;
    #pragma unroll
    for (int mi = 0; mi < 4; ++mi)
      #pragma unroll
      for (int ni = 0; ni < 4; ++ni)
        #pragma unroll
        for (int r = 0; r < 4; ++r){
          int m = m0 + wm + mi*16 + quad*4 + r;
          int n = n0 + wn + ni*16 + lm;
          int b = m >> 11, s = m & 2047, h = n >> 6, d = n & 63;
          outz[(((size_t)(b*NH + h))*SEQ + s)*DKH + d] = f2bf(acc[z][mi][ni][r] * scale);
        }
  }
  // z=2 (V): [bh][d][s], 4 consecutive s per thread -> uint2 store
  {
    u16* outz = QKV + (size_t)2 * ZSTRIDE;
    #pragma unroll
    for (int mi = 0; mi < 4; ++mi)
      #pragma unroll
      for (int ni = 0; ni < 4; ++ni){
        int mbase = m0 + wm + mi*16 + quad*4;
        int n = n0 + wn + ni*16 + lm;
        int b = mbase >> 11, sb = mbase & 2047;
        int h = n >> 6, d = n & 63;
        u16* dst = outz + (((size_t)(b*NH + h))*DKH + d)*SEQ + sb;
        uint2 pv;
        pv.x = pk2(acc[2][mi][ni][0], acc[2][mi][ni][1]);
        pv.y = pk2(acc[2][mi][ni][2], acc[2][mi][ni][3]);
        *reinterpret_cast<uint2*>(dst) = pv;
      }
  }
}

// Final: out = Attn * Wo^T, fp32 out [b*s][e]. grid (64, 8). BK=64 (R6: -4 us),
// source-side XOR swizzle on staging, same XOR on read. Counted vmcnt(8).
__global__ __launch_bounds__(256) void gemm_out(const u16* __restrict__ A,
    const u16* __restrict__ W, float* __restrict__ C){
  __shared__ __attribute__((aligned(16))) u16 As[2*128*64];   // 32 KB
  __shared__ __attribute__((aligned(16))) u16 Bs[2*128*64];   // 32 KB
  const int tid = threadIdx.x, lane = tid & 63, w = tid >> 6;
  const int lm = lane & 15, quad = lane >> 4;
  const int wm = (w & 1) * 64, wn = (w >> 1) * 64;
  const int m0 = blockIdx.x * 128, n0 = blockIdx.y * 128;

  const int srow = tid >> 3;
  const int ssw  = ((tid & 7) ^ (srow & 7)) * 8;   // u16 col offset
  const u16* Ab = A + (size_t)(m0 + srow)*EMBED + ssw;
  const u16* Bb = W + (size_t)(n0 + srow)*EMBED + ssw;

  floatx4 acc[4][4];
  #pragma unroll
  for (int mi = 0; mi < 4; ++mi)
    #pragma unroll
    for (int ni = 0; ni < 4; ++ni)
      acc[mi][ni] = (floatx4){0.f, 0.f, 0.f, 0.f};

  #pragma unroll
  for (int j = 0; j < 4; ++j){
    gl_lds16(Ab + (size_t)j*32*EMBED, As + (j*256 + tid)*8);
    gl_lds16(Bb + (size_t)j*32*EMBED, Bs + (j*256 + tid)*8);
  }

  for (int kt = 0; kt < EMBED/64; ++kt){
    const int cur = kt & 1;
    __builtin_amdgcn_s_barrier();          // B1
    CFENCE;
    if (kt + 1 < EMBED/64){
      const int k0 = (kt + 1) * 64;
      #pragma unroll
      for (int j = 0; j < 4; ++j){
        gl_lds16(Ab + (size_t)j*32*EMBED + k0, As + (cur^1)*8192 + (j*256 + tid)*8);
        gl_lds16(Bb + (size_t)j*32*EMBED + k0, Bs + (cur^1)*8192 + (j*256 + tid)*8);
      }
      asm volatile("s_waitcnt vmcnt(8)" ::: "memory");
    } else {
      asm volatile("s_waitcnt vmcnt(0)" ::: "memory");
    }
    __builtin_amdgcn_s_barrier();          // B2
    CFENCE;
    const u16* Ac = As + cur*8192;
    const u16* Bc = Bs + cur*8192;
    #pragma unroll
    for (int kh = 0; kh < 2; ++kh){
      const int us = ((kh*4 + quad) ^ (lm & 7)) * 8;
      bf16x8 af[4], bf[4];
      #pragma unroll
      for (int mi = 0; mi < 4; ++mi)
        af[mi] = ld_frag(&Ac[(wm + mi*16 + lm)*64 + us]);
      #pragma unroll
      for (int ni = 0; ni < 4; ++ni)
        bf[ni] = ld_frag(&Bc[(wn + ni*16 + lm)*64 + us]);
      #pragma unroll
      for (int mi = 0; mi < 4; ++mi)
        #pragma unroll
        for (int ni = 0; ni < 4; ++ni)
          acc[mi][ni] = mfma16(af[mi], bf[ni], acc[mi][ni]);
    }
  }

  #pragma unroll
  for (int mi = 0; mi < 4; ++mi)
    #pragma unroll
    for (int ni = 0; ni < 4; ++ni)
      #pragma unroll
      for (int r = 0; r < 4; ++r){
        int m = m0 + wm + mi*16 + quad*4 + r;
        int n = n0 + wn + ni*16 + lm;
        C[(size_t)m*EMBED + n] = acc[mi][ni][r];
      }
}

// =================== fused attention (P stays in registers) ===================
// grid (64, 16): x = bh, y = q-block of 128 rows. 4 waves x 32 q (2 q-tiles).
// Keys chunked by 64, K/V double-buffered DMA. R7: widest-DAG body (kept,
// ~neutral). This round: counted vmcnt(4) double-barrier instead of
// __syncthreads' full drain. 4 DMA/thread/kt.
#define KSS 520
__global__ __launch_bounds__(256, 4) void attn_kernel(const u16* __restrict__ QKV,
                                                      u16* __restrict__ Out){
  __shared__ __attribute__((aligned(16))) u16 Ks[2][8*KSS];   // 16.6 KB
  __shared__ __attribute__((aligned(16))) u16 Vs[2][64*64];   // 16.4 KB

  const int tid = threadIdx.x, lane = tid & 63, w = tid >> 6;
  const int lm = lane & 15, quad = lane >> 4;
  const int bh = blockIdx.x;
  const int q0 = blockIdx.y * 128;
  const u16* Qh = QKV + (size_t)bh * SEQ * DKH;
  const u16* Kh = QKV + ZSTRIDE + (size_t)bh * SEQ * DKH;
  const u16* Vh = QKV + 2*ZSTRIDE + (size_t)bh * DKH * SEQ;  // [d][s] plain

  const int sK = tid & 63, cK = tid >> 6;
  const int dV = tid >> 3, gV = tid & 7;
  const size_t vsrc0 = (size_t)dV * SEQ + ((gV ^ (dV & 7)) * 8);
  const size_t vsrc1 = vsrc0 + (size_t)32 * SEQ;

  bf16x8 qf[2][2];
  #pragma unroll
  for (int qt = 0; qt < 2; ++qt)
    #pragma unroll
    for (int st = 0; st < 2; ++st)
      qf[qt][st] = ld_frag(Qh + (size_t)(q0 + w*32 + qt*16 + lm)*DKH + st*32 + quad*8);

  const uint4 ONESW = {0x3F803F80u, 0x3F803F80u, 0x3F803F80u, 0x3F803F80u};
  const bf16x8 ones8 = __builtin_bit_cast(bf16x8, ONESW);    // bf16 1.0 x8

  floatx4 o[2][4], lac[2];
  #pragma unroll
  for (int qt = 0; qt < 2; ++qt){
    lac[qt] = (floatx4){0.f, 0.f, 0.f, 0.f};
    #pragma unroll
    for (int dt = 0; dt < 4; ++dt) o[qt][dt] = (floatx4){0.f, 0.f, 0.f, 0.f};
  }

  gl_lds16(Kh + (size_t)sK*DKH + cK*8,     Ks[0] + cK*KSS + sK*8);
  gl_lds16(Kh + (size_t)sK*DKH + (cK+4)*8, Ks[0] + (cK+4)*KSS + sK*8);
  gl_lds16(Vh + vsrc0,                     Vs[0] + tid*8);
  gl_lds16(Vh + vsrc1,                     Vs[0] + 2048 + tid*8);

  for (int kt = 0; kt < SEQ/64; ++kt){
    const int cur = kt & 1;
    __builtin_amdgcn_s_barrier();          // B1: all waves done reading cur^1
    CFENCE;
    if (kt + 1 < SEQ/64){
      const int nk0 = (kt + 1) * 64;
      gl_lds16(Kh + (size_t)(nk0 + sK)*DKH + cK*8,     Ks[cur^1] + cK*KSS + sK*8);
      gl_lds16(Kh + (size_t)(nk0 + sK)*DKH + (cK+4)*8, Ks[cur^1] + (cK+4)*KSS + sK*8);
      gl_lds16(Vh + vsrc0 + nk0,                       Vs[cur^1] + tid*8);
      gl_lds16(Vh + vsrc1 + nk0,                       Vs[cur^1] + 2048 + tid*8);
      asm volatile("s_waitcnt vmcnt(4)" ::: "memory");
    } else {
      asm volatile("s_waitcnt vmcnt(0)" ::: "memory");
    }
    __builtin_amdgcn_s_barrier();          // B2: cur landed block-wide
    CFENCE;
    const u16* Kc = Ks[cur];
    const u16* Vc = Vs[cur];

    // ---- widest-DAG schedule for this kt ----
    auto QK = [&](int t, floatx4& s0, floatx4& s1){
      bf16x8 kf0 = ld_frag(&Kc[quad*KSS     + (t*16 + lm)*8]);
      bf16x8 kf1 = ld_frag(&Kc[(quad+4)*KSS + (t*16 + lm)*8]);
      floatx4 a = (floatx4){0.f,0.f,0.f,0.f};
      a = mfma16(kf0, qf[0][0], a);
      a = mfma16(kf1, qf[0][1], a);
      s0 = a;
      floatx4 b = (floatx4){0.f,0.f,0.f,0.f};
      b = mfma16(kf0, qf[1][0], b);
      b = mfma16(kf1, qf[1][1], b);
      s1 = b;
    };
    auto EXP = [&](const floatx4& s) -> uint2 {
      uint2 p;
      p.x = pk2(__builtin_amdgcn_exp2f(s[0]), __builtin_amdgcn_exp2f(s[1]));
      p.y = pk2(__builtin_amdgcn_exp2f(s[2]), __builtin_amdgcn_exp2f(s[3]));
      return p;
    };

    floatx4 sa0, sa1, sb0, sb1, sc0, sc1, sd0, sd1;
    uint2 e00, e01, e10, e11, e20, e21, e30, e31;   // e{tile}{qt}

    QK(0, sa0, sa1);                 // 4 MFMA
    QK(1, sb0, sb1);                 // 4 MFMA
    e00 = EXP(sa0); e01 = EXP(sa1);  // 8 exp2
    QK(2, sc0, sc1);                 // 4 MFMA
    e10 = EXP(sb0); e11 = EXP(sb1);  // 8 exp2
    QK(3, sd0, sd1);                 // 4 MFMA
    e20 = EXP(sc0); e21 = EXP(sc1);  // 8 exp2

    // PV u=0 (tiles 0,1)
    {
      uint4 pp0 = {e00.x, e00.y, e10.x, e10.y};
      uint4 pp1 = {e01.x, e01.y, e11.x, e11.y};
      bf16x8 pf0 = __builtin_bit_cast(bf16x8, pp0);
      bf16x8 pf1 = __builtin_bit_cast(bf16x8, pp1);
      lac[0] = mfma16(pf0, ones8, lac[0]);
      lac[1] = mfma16(pf1, ones8, lac[1]);
      const int cg0 = (((0 + (quad >> 1)) ^ (lm & 7)) * 8) + (quad & 1) * 4;
      const int cg1 = (((2 + (quad >> 1)) ^ (lm & 7)) * 8) + (quad & 1) * 4;
      #pragma unroll
      for (int dt = 0; dt < 4; ++dt){
        uint2 vlo = *(const uint2*)(Vc + (dt*16 + lm)*64 + cg0);
        uint2 vhi = *(const uint2*)(Vc + (dt*16 + lm)*64 + cg1);
        uint4 vv = {vlo.x, vlo.y, vhi.x, vhi.y};
        bf16x8 vb = __builtin_bit_cast(bf16x8, vv);
        o[0][dt] = mfma16(pf0, vb, o[0][dt]);
        o[1][dt] = mfma16(pf1, vb, o[1][dt]);
      }
    }

    e30 = EXP(sd0); e31 = EXP(sd1);  // 8 exp2 (independent of PV u=0)

    // PV u=1 (tiles 2,3)
    {
      uint4 pp0 = {e20.x, e20.y, e30.x, e30.y};
      uint4 pp1 = {e21.x, e21.y, e31.x, e31.y};
      bf16x8 pf0 = __builtin_bit_cast(bf16x8, pp0);
      bf16x8 pf1 = __builtin_bit_cast(bf16x8, pp1);
      lac[0] = mfma16(pf0, ones8, lac[0]);
      lac[1] = mfma16(pf1, ones8, lac[1]);
      const int cg0 = (((4 + (quad >> 1)) ^ (lm & 7)) * 8) + (quad & 1) * 4;
      const int cg1 = (((6 + (quad >> 1)) ^ (lm & 7)) * 8) + (quad & 1) * 4;
      #pragma unroll
      for (int dt = 0; dt < 4; ++dt){
        uint2 vlo = *(const uint2*)(Vc + (dt*16 + lm)*64 + cg0);
        uint2 vhi = *(const uint2*)(Vc + (dt*16 + lm)*64 + cg1);
        uint4 vv = {vlo.x, vlo.y, vhi.x, vhi.y};
        bf16x8 vb = __builtin_bit_cast(bf16x8, vv);
        o[0][dt] = mfma16(pf0, vb, o[0][dt]);
        o[1][dt] = mfma16(pf1, vb, o[1][dt]);
      }
    }
  }

  const int bI = bh >> 4, h = bh & 15;
  #pragma unroll
  for (int qt = 0; qt < 2; ++qt){
    floatx4 inv;
    #pragma unroll
    for (int r = 0; r < 4; ++r) inv[r] = __builtin_amdgcn_rcpf(lac[qt][r]);
    #pragma unroll
    for (int dt = 0; dt < 4; ++dt)
      #pragma unroll
      for (int r = 0; r < 4; ++r){
        int s = q0 + w*32 + qt*16 + quad*4 + r;
        Out[((size_t)(bI*SEQ + s))*EMBED + h*DKH + dt*16 + lm] = f2bf(o[qt][dt][r] * inv[r]);
      }
  }
}

// =================== launch ===================
extern "C" void kernel_launch(void* const* d_in, const int* in_sizes, int n_in,
                              void* d_out, int out_size, void* d_ws, size_t ws_size,
                              hipStream_t stream){
  const float* x  = (const float*)d_in[0];
  const float* Wq = (const float*)d_in[1];
  const float* Wk = (const float*)d_in[2];
  const float* Wv = (const float*)d_in[3];
  const float* Wo = (const float*)d_in[4];
  float* out = (float*)d_out;

  char* ws = (char*)d_ws;
  u16* Xb  = (u16*)ws;                          // 16 MB
  u16* Wqb = (u16*)(ws + (size_t)16777216);     // 4 x 2 MB
  u16* Wkb = Wqb + 1048576;
  u16* Wvb = Wkb + 1048576;
  u16* Wob = Wvb + 1048576;
  u16* QKV = (u16*)(ws + (size_t)25165824);     // 3 x 16.78 MB
  u16* At  = (u16*)(ws + (size_t)75497472);     // 16 MB

  cvt_all<<<12288, 256, 0, stream>>>(x, Wq, Wk, Wv, Wo, Xb, Wqb, Wkb, Wvb, Wob);
  gemm_qkv<<<dim3(64, 8), 256, 0, stream>>>(Xb, Wqb, Wkb, Wvb, QKV);
  attn_kernel<<<dim3(64, 16), 256, 0, stream>>>(QKV, At);
  gemm_out<<<dim3(64, 8), 256, 0, stream>>>(At, Wob, out);
}

// Round 9
// 247.308 us; speedup vs baseline: 1.0147x; 1.0008x over previous
//
#include <hip/hip_runtime.h>
#include <hip/hip_bf16.h>

typedef unsigned short u16;
typedef unsigned int   u32;
typedef __attribute__((ext_vector_type(8))) __bf16 bf16x8;
typedef __attribute__((ext_vector_type(2))) __bf16 bf16x2;
typedef __attribute__((ext_vector_type(8))) u16    ushort8v;
typedef __attribute__((ext_vector_type(2))) float  f32x2;
typedef __attribute__((ext_vector_type(4))) float  floatx4;

#define EMBED 1024
#define SEQ   2048
#define BATCH 4
#define NH    16
#define DKH   64
#define BHN   (BATCH*NH)              // 64
#define ZSTRIDE ((size_t)BHN*SEQ*DKH) // elements per Q/K/V plane

// ---- fp32 -> bf16 RTNE ----
__device__ __forceinline__ u16 f2bf(float f){
  union { float f; unsigned u; } v; v.f = f;
  unsigned r = (v.u + 0x7FFFu + ((v.u >> 16) & 1u)) >> 16;
  return (u16)r;
}
// packed pair via v_cvt_pk_bf16_f32
__device__ __forceinline__ u32 pk2(float a, float b){
  f32x2 v = {a, b};
  return __builtin_bit_cast(u32, __builtin_convertvector(v, bf16x2));
}

__device__ __forceinline__ bf16x8 ld_frag(const u16* p){
  return __builtin_bit_cast(bf16x8, *(const ushort8v*)p);
}

__device__ __forceinline__ floatx4 mfma16(bf16x8 a, bf16x8 b, floatx4 c){
  return __builtin_amdgcn_mfma_f32_16x16x32_bf16(a, b, c, 0, 0, 0);
}

// async global->LDS, 16B per lane; LDS dst must be uniform_base + lane*16
__device__ __forceinline__ void gl_lds16(const u16* g, u16* l){
  __builtin_amdgcn_global_load_lds((const __attribute__((address_space(1))) void*)g,
                                   (__attribute__((address_space(3))) void*)l,
                                   16, 0, 0);
}

// T4 counted-vmcnt barrier discipline (m201/m218 pattern):
//   B1 (all waves done READING buf[cur^1]) -> issue prefetch into cur^1 ->
//   s_waitcnt vmcnt(N) (buf[cur] landed, prefetch stays IN FLIGHT) ->
//   B2 (every wave's counted wait passed => buf[cur] landed block-wide) ->
//   compute. Replaces __syncthreads' full vmcnt(0) drain.
#define CFENCE asm volatile("" ::: "memory")

// =================== fused cast kernel ===================
__global__ __launch_bounds__(256) void cvt_all(const float* __restrict__ x,
    const float* __restrict__ wq, const float* __restrict__ wk,
    const float* __restrict__ wv, const float* __restrict__ wo,
    u16* __restrict__ Xb, u16* __restrict__ Wqb, u16* __restrict__ Wkb,
    u16* __restrict__ Wvb, u16* __restrict__ Wob){
  int b = blockIdx.x;
  const float* src; u16* dst; int i;
  if (b < 8192){ src = x; dst = Xb; i = b*256 + threadIdx.x; }
  else {
    int k = (b - 8192) >> 10, r = (b - 8192) & 1023;
    src = (k==0) ? wq : (k==1) ? wk : (k==2) ? wv : wo;
    dst = (k==0) ? Wqb : (k==1) ? Wkb : (k==2) ? Wvb : Wob;
    i = r*256 + threadIdx.x;
  }
  float4 v = ((const float4*)src)[i];
  ushort4 o;
  o.x = f2bf(v.x); o.y = f2bf(v.y); o.z = f2bf(v.z); o.w = f2bf(v.w);
  ((ushort4*)dst)[i] = o;
}

// ============== fused QKV projection (R3-v1 + counted vmcnt) ===================
// grid (64, 8): x = m-tile (128 rows), y = n-tile (128 cols). Q,K,V share the
// A operand -> stage X ONCE per kt, 3 B tiles, 48 MFMA/wave/kt per barrier.
// LDS = 64 KB -> 2 blocks/CU. 8 DMA/thread/kt -> steady vmcnt(8).
#define QSCALE 0.1803368801111204f   // 0.125 * log2(e)
__global__ __launch_bounds__(256, 2) void gemm_qkv(const u16* __restrict__ X,
    const u16* __restrict__ Wq, const u16* __restrict__ Wk, const u16* __restrict__ Wv,
    u16* __restrict__ QKV){
  __shared__ __attribute__((aligned(16))) u16 As[2*128*32];      // 16 KB
  __shared__ __attribute__((aligned(16))) u16 Bs[3][2*128*32];   // 48 KB

  const int tid = threadIdx.x, lane = tid & 63, w = tid >> 6;
  const int lm = lane & 15, quad = lane >> 4;
  const int wm = (w & 1) * 64, wn = (w >> 1) * 64;
  const int m0 = blockIdx.x * 128, n0 = blockIdx.y * 128;
  const int row0 = tid >> 2, kc = tid & 3;

  const u16* A0 = X  + (size_t)(m0 + row0)*EMBED + kc*8;   // +64*EMBED for r=1
  const u16* B0[3] = {
    Wq + (size_t)(n0 + row0)*EMBED + kc*8,
    Wk + (size_t)(n0 + row0)*EMBED + kc*8,
    Wv + (size_t)(n0 + row0)*EMBED + kc*8 };

  floatx4 acc[3][4][4];
  #pragma unroll
  for (int z = 0; z < 3; ++z)
    #pragma unroll
    for (int mi = 0; mi < 4; ++mi)
      #pragma unroll
      for (int ni = 0; ni < 4; ++ni)
        acc[z][mi][ni] = (floatx4){0.f, 0.f, 0.f, 0.f};

  // prologue: stage kt=0 into buffer 0 (8 DMAs in flight)
  gl_lds16(A0,            As + tid*8);
  gl_lds16(A0 + 64*EMBED, As + (256 + tid)*8);
  #pragma unroll
  for (int z = 0; z < 3; ++z){
    gl_lds16(B0[z],            Bs[z] + tid*8);
    gl_lds16(B0[z] + 64*EMBED, Bs[z] + (256 + tid)*8);
  }

  for (int kt = 0; kt < EMBED/32; ++kt){
    const int cur = kt & 1;
    __builtin_amdgcn_s_barrier();          // B1: all waves done reading cur^1
    CFENCE;
    if (kt + 1 < EMBED/32){
      const int k0 = (kt + 1) * 32;
      gl_lds16(A0 + k0,            As + (cur^1)*4096 + tid*8);
      gl_lds16(A0 + 64*EMBED + k0, As + (cur^1)*4096 + (256 + tid)*8);
      #pragma unroll
      for (int z = 0; z < 3; ++z){
        gl_lds16(B0[z] + k0,            Bs[z] + (cur^1)*4096 + tid*8);
        gl_lds16(B0[z] + 64*EMBED + k0, Bs[z] + (cur^1)*4096 + (256 + tid)*8);
      }
      asm volatile("s_waitcnt vmcnt(8)" ::: "memory");   // cur landed, 8 in flight
    } else {
      asm volatile("s_waitcnt vmcnt(0)" ::: "memory");
    }
    __builtin_amdgcn_s_barrier();          // B2: cur landed block-wide
    CFENCE;
    const u16* Ac = As + cur*4096;
    bf16x8 af[4];
    #pragma unroll
    for (int mi = 0; mi < 4; ++mi)
      af[mi] = ld_frag(&Ac[(wm + mi*16 + lm)*32 + quad*8]);
    #pragma unroll
    for (int z = 0; z < 3; ++z){
      const u16* Bc = Bs[z] + cur*4096;
      bf16x8 bfz[4];
      #pragma unroll
      for (int ni = 0; ni < 4; ++ni)
        bfz[ni] = ld_frag(&Bc[(wn + ni*16 + lm)*32 + quad*8]);
      #pragma unroll
      for (int mi = 0; mi < 4; ++mi)
        #pragma unroll
        for (int ni = 0; ni < 4; ++ni)
          acc[z][mi][ni] = mfma16(af[mi], bfz[ni], acc[z][mi][ni]);
    }
  }

  // ---- epilogues: direct stores ----
  // z=0 (Q, scaled) and z=1 (K): [bh][s][d]
  #pragma unroll
  for (int z = 0; z < 2; ++z){
    const float scale = (z == 0) ? QSCALE : 1.0f;
    u16* outz = QKV + (size_t)z * ZSTRIDE;
    #pragma unroll
    for (int mi = 0; mi < 4; ++mi)
      #pragma unroll
      for (int ni = 0; ni < 4; ++ni)
        #pragma unroll
        for (int r = 0; r < 4; ++r){
          int m = m0 + wm + mi*16 + quad*4 + r;
          int n = n0 + wn + ni*16 + lm;
          int b = m >> 11, s = m & 2047, h = n >> 6, d = n & 63;
          outz[(((size_t)(b*NH + h))*SEQ + s)*DKH + d] = f2bf(acc[z][mi][ni][r] * scale);
        }
  }
  // z=2 (V): [bh][d][s], 4 consecutive s per thread -> uint2 store
  {
    u16* outz = QKV + (size_t)2 * ZSTRIDE;
    #pragma unroll
    for (int mi = 0; mi < 4; ++mi)
      #pragma unroll
      for (int ni = 0; ni < 4; ++ni){
        int mbase = m0 + wm + mi*16 + quad*4;
        int n = n0 + wn + ni*16 + lm;
        int b = mbase >> 11, sb = mbase & 2047;
        int h = n >> 6, d = n & 63;
        u16* dst = outz + (((size_t)(b*NH + h))*DKH + d)*SEQ + sb;
        uint2 pv;
        pv.x = pk2(acc[2][mi][ni][0], acc[2][mi][ni][1]);
        pv.y = pk2(acc[2][mi][ni][2], acc[2][mi][ni][3]);
        *reinterpret_cast<uint2*>(dst) = pv;
      }
  }
}

// Final: out = Attn * Wo^T, fp32 out [b*s][e]. grid (64, 8). BK=64,
// source-side XOR swizzle on staging, same XOR on read. Counted vmcnt(8).
__global__ __launch_bounds__(256) void gemm_out(const u16* __restrict__ A,
    const u16* __restrict__ W, float* __restrict__ C){
  __shared__ __attribute__((aligned(16))) u16 As[2*128*64];   // 32 KB
  __shared__ __attribute__((aligned(16))) u16 Bs[2*128*64];   // 32 KB
  const int tid = threadIdx.x, lane = tid & 63, w = tid >> 6;
  const int lm = lane & 15, quad = lane >> 4;
  const int wm = (w & 1) * 64, wn = (w >> 1) * 64;
  const int m0 = blockIdx.x * 128, n0 = blockIdx.y * 128;

  const int srow = tid >> 3;
  const int ssw  = ((tid & 7) ^ (srow & 7)) * 8;   // u16 col offset
  const u16* Ab = A + (size_t)(m0 + srow)*EMBED + ssw;
  const u16* Bb = W + (size_t)(n0 + srow)*EMBED + ssw;

  floatx4 acc[4][4];
  #pragma unroll
  for (int mi = 0; mi < 4; ++mi)
    #pragma unroll
    for (int ni = 0; ni < 4; ++ni)
      acc[mi][ni] = (floatx4){0.f, 0.f, 0.f, 0.f};

  #pragma unroll
  for (int j = 0; j < 4; ++j){
    gl_lds16(Ab + (size_t)j*32*EMBED, As + (j*256 + tid)*8);
    gl_lds16(Bb + (size_t)j*32*EMBED, Bs + (j*256 + tid)*8);
  }

  for (int kt = 0; kt < EMBED/64; ++kt){
    const int cur = kt & 1;
    __builtin_amdgcn_s_barrier();          // B1
    CFENCE;
    if (kt + 1 < EMBED/64){
      const int k0 = (kt + 1) * 64;
      #pragma unroll
      for (int j = 0; j < 4; ++j){
        gl_lds16(Ab + (size_t)j*32*EMBED + k0, As + (cur^1)*8192 + (j*256 + tid)*8);
        gl_lds16(Bb + (size_t)j*32*EMBED + k0, Bs + (cur^1)*8192 + (j*256 + tid)*8);
      }
      asm volatile("s_waitcnt vmcnt(8)" ::: "memory");
    } else {
      asm volatile("s_waitcnt vmcnt(0)" ::: "memory");
    }
    __builtin_amdgcn_s_barrier();          // B2
    CFENCE;
    const u16* Ac = As + cur*8192;
    const u16* Bc = Bs + cur*8192;
    #pragma unroll
    for (int kh = 0; kh < 2; ++kh){
      const int us = ((kh*4 + quad) ^ (lm & 7)) * 8;
      bf16x8 af[4], bf[4];
      #pragma unroll
      for (int mi = 0; mi < 4; ++mi)
        af[mi] = ld_frag(&Ac[(wm + mi*16 + lm)*64 + us]);
      #pragma unroll
      for (int ni = 0; ni < 4; ++ni)
        bf[ni] = ld_frag(&Bc[(wn + ni*16 + lm)*64 + us]);
      #pragma unroll
      for (int mi = 0; mi < 4; ++mi)
        #pragma unroll
        for (int ni = 0; ni < 4; ++ni)
          acc[mi][ni] = mfma16(af[mi], bf[ni], acc[mi][ni]);
    }
  }

  #pragma unroll
  for (int mi = 0; mi < 4; ++mi)
    #pragma unroll
    for (int ni = 0; ni < 4; ++ni)
      #pragma unroll
      for (int r = 0; r < 4; ++r){
        int m = m0 + wm + mi*16 + quad*4 + r;
        int n = n0 + wn + ni*16 + lm;
        C[(size_t)m*EMBED + n] = acc[mi][ni][r];
      }
}

// =================== fused attention (P stays in registers) ===================
// grid (64, 8): x = bh, y = q-block of 256 rows. 4 waves x 64 q (4 q-tiles).
// R8 diagnosis: attn is LDS-traffic-bound, not schedule-bound (3 schedule
// nulls; per-CU-kt budget: MFMA 2794 + VALU ~2000 + LDS ~2500 cyc vs wall
// 6264). Every wave reads the FULL K/V tiles; with 4 blocks/CU that's 16
// full-tile reads/CU/kt. Fix: 4 q-tiles per wave -> same per-wave LDS bytes
// feed 2x the MFMAs; 2 blocks/CU -> LDS traffic per CU-kt HALVES, DMA issues
// halve, barrier instances halve. ~175 unified regs -> launch_bounds(256,2).
// Counted vmcnt(4) double-barrier kept. Accumulation order per output
// element unchanged -> bit-identical results.
#define KSS 520
__global__ __launch_bounds__(256, 2) void attn_kernel(const u16* __restrict__ QKV,
                                                      u16* __restrict__ Out){
  __shared__ __attribute__((aligned(16))) u16 Ks[2][8*KSS];   // 16.6 KB
  __shared__ __attribute__((aligned(16))) u16 Vs[2][64*64];   // 16.4 KB

  const int tid = threadIdx.x, lane = tid & 63, w = tid >> 6;
  const int lm = lane & 15, quad = lane >> 4;
  const int bh = blockIdx.x;
  const int q0 = blockIdx.y * 256;
  const u16* Qh = QKV + (size_t)bh * SEQ * DKH;
  const u16* Kh = QKV + ZSTRIDE + (size_t)bh * SEQ * DKH;
  const u16* Vh = QKV + 2*ZSTRIDE + (size_t)bh * DKH * SEQ;  // [d][s] plain

  const int sK = tid & 63, cK = tid >> 6;
  const int dV = tid >> 3, gV = tid & 7;
  const size_t vsrc0 = (size_t)dV * SEQ + ((gV ^ (dV & 7)) * 8);
  const size_t vsrc1 = vsrc0 + (size_t)32 * SEQ;

  // Q fragments: 4 q-tiles per wave (64 q rows), B-operand layout
  bf16x8 qf[4][2];
  #pragma unroll
  for (int qt = 0; qt < 4; ++qt)
    #pragma unroll
    for (int st = 0; st < 2; ++st)
      qf[qt][st] = ld_frag(Qh + (size_t)(q0 + w*64 + qt*16 + lm)*DKH + st*32 + quad*8);

  const uint4 ONESW = {0x3F803F80u, 0x3F803F80u, 0x3F803F80u, 0x3F803F80u};
  const bf16x8 ones8 = __builtin_bit_cast(bf16x8, ONESW);    // bf16 1.0 x8

  floatx4 o[4][4], lac[4];
  #pragma unroll
  for (int qt = 0; qt < 4; ++qt){
    lac[qt] = (floatx4){0.f, 0.f, 0.f, 0.f};
    #pragma unroll
    for (int dt = 0; dt < 4; ++dt) o[qt][dt] = (floatx4){0.f, 0.f, 0.f, 0.f};
  }

  gl_lds16(Kh + (size_t)sK*DKH + cK*8,     Ks[0] + cK*KSS + sK*8);
  gl_lds16(Kh + (size_t)sK*DKH + (cK+4)*8, Ks[0] + (cK+4)*KSS + sK*8);
  gl_lds16(Vh + vsrc0,                     Vs[0] + tid*8);
  gl_lds16(Vh + vsrc1,                     Vs[0] + 2048 + tid*8);

  for (int kt = 0; kt < SEQ/64; ++kt){
    const int cur = kt & 1;
    __builtin_amdgcn_s_barrier();          // B1: all waves done reading cur^1
    CFENCE;
    if (kt + 1 < SEQ/64){
      const int nk0 = (kt + 1) * 64;
      gl_lds16(Kh + (size_t)(nk0 + sK)*DKH + cK*8,     Ks[cur^1] + cK*KSS + sK*8);
      gl_lds16(Kh + (size_t)(nk0 + sK)*DKH + (cK+4)*8, Ks[cur^1] + (cK+4)*KSS + sK*8);
      gl_lds16(Vh + vsrc0 + nk0,                       Vs[cur^1] + tid*8);
      gl_lds16(Vh + vsrc1 + nk0,                       Vs[cur^1] + 2048 + tid*8);
      asm volatile("s_waitcnt vmcnt(4)" ::: "memory");
    } else {
      asm volatile("s_waitcnt vmcnt(0)" ::: "memory");
    }
    __builtin_amdgcn_s_barrier();          // B2: cur landed block-wide
    CFENCE;
    const u16* Kc = Ks[cur];
    const u16* Vc = Vs[cur];

    #pragma unroll
    for (int u = 0; u < 2; ++u){           // pair of 16-key tiles = 32 keys
      uint2 e[4][2];                       // [qt][half]: exp'd P, 4 bf16 each
      #pragma unroll
      for (int half = 0; half < 2; ++half){
        const int t = u*2 + half;
        bf16x8 kf0 = ld_frag(&Kc[quad*KSS     + (t*16 + lm)*8]);
        bf16x8 kf1 = ld_frag(&Kc[(quad+4)*KSS + (t*16 + lm)*8]);
        #pragma unroll
        for (int qt = 0; qt < 4; ++qt){
          floatx4 s = (floatx4){0.f,0.f,0.f,0.f};
          s = mfma16(kf0, qf[qt][0], s);
          s = mfma16(kf1, qf[qt][1], s);
          e[qt][half].x = pk2(__builtin_amdgcn_exp2f(s[0]), __builtin_amdgcn_exp2f(s[1]));
          e[qt][half].y = pk2(__builtin_amdgcn_exp2f(s[2]), __builtin_amdgcn_exp2f(s[3]));
        }
      }
      // pack K=32 A-frags: slots 0-3 <- tile 2u, 4-7 <- tile 2u+1
      bf16x8 pf[4];
      #pragma unroll
      for (int qt = 0; qt < 4; ++qt){
        uint4 pp = {e[qt][0].x, e[qt][0].y, e[qt][1].x, e[qt][1].y};
        pf[qt] = __builtin_bit_cast(bf16x8, pp);
      }
      // l += P*1 (K=32)
      #pragma unroll
      for (int qt = 0; qt < 4; ++qt)
        lac[qt] = mfma16(pf[qt], ones8, lac[qt]);
      // O += P*V : B-frag = concat of the two tiles' b64 reads
      const int cg0 = (((u*4     + (quad >> 1)) ^ (lm & 7)) * 8) + (quad & 1) * 4;
      const int cg1 = (((u*4 + 2 + (quad >> 1)) ^ (lm & 7)) * 8) + (quad & 1) * 4;
      #pragma unroll
      for (int dt = 0; dt < 4; ++dt){
        uint2 vlo = *(const uint2*)(Vc + (dt*16 + lm)*64 + cg0);
        uint2 vhi = *(const uint2*)(Vc + (dt*16 + lm)*64 + cg1);
        uint4 vv = {vlo.x, vlo.y, vhi.x, vhi.y};
        bf16x8 vb = __builtin_bit_cast(bf16x8, vv);
        #pragma unroll
        for (int qt = 0; qt < 4; ++qt)
          o[qt][dt] = mfma16(pf[qt], vb, o[qt][dt]);
      }
    }
  }

  const int bI = bh >> 4, h = bh & 15;
  #pragma unroll
  for (int qt = 0; qt < 4; ++qt){
    floatx4 inv;
    #pragma unroll
    for (int r = 0; r < 4; ++r) inv[r] = __builtin_amdgcn_rcpf(lac[qt][r]);
    #pragma unroll
    for (int dt = 0; dt < 4; ++dt)
      #pragma unroll
      for (int r = 0; r < 4; ++r){
        int s = q0 + w*64 + qt*16 + quad*4 + r;
        Out[((size_t)(bI*SEQ + s))*EMBED + h*DKH + dt*16 + lm] = f2bf(o[qt][dt][r] * inv[r]);
      }
  }
}

// =================== launch ===================
extern "C" void kernel_launch(void* const* d_in, const int* in_sizes, int n_in,
                              void* d_out, int out_size, void* d_ws, size_t ws_size,
                              hipStream_t stream){
  const float* x  = (const float*)d_in[0];
  const float* Wq = (const float*)d_in[1];
  const float* Wk = (const float*)d_in[2];
  const float* Wv = (const float*)d_in[3];
  const float* Wo = (const float*)d_in[4];
  float* out = (float*)d_out;

  char* ws = (char*)d_ws;
  u16* Xb  = (u16*)ws;                          // 16 MB
  u16* Wqb = (u16*)(ws + (size_t)16777216);     // 4 x 2 MB
  u16* Wkb = Wqb + 1048576;
  u16* Wvb = Wkb + 1048576;
  u16* Wob = Wvb + 1048576;
  u16* QKV = (u16*)(ws + (size_t)25165824);     // 3 x 16.78 MB
  u16* At  = (u16*)(ws + (size_t)75497472);     // 16 MB

  cvt_all<<<12288, 256, 0, stream>>>(x, Wq, Wk, Wv, Wo, Xb, Wqb, Wkb, Wvb, Wob);
  gemm_qkv<<<dim3(64, 8), 256, 0, stream>>>(Xb, Wqb, Wkb, Wvb, QKV);
  attn_kernel<<<dim3(64, 8), 256, 0, stream>>>(QKV, At);
  gemm_out<<<dim3(64, 8), 256, 0, stream>>>(At, Wob, out);
}

// Round 10
// 241.340 us; speedup vs baseline: 1.0397x; 1.0247x over previous
//
#include <hip/hip_runtime.h>
#include <hip/hip_bf16.h>

typedef unsigned short u16;
typedef unsigned int   u32;
typedef __attribute__((ext_vector_type(8))) __bf16 bf16x8;
typedef __attribute__((ext_vector_type(2))) __bf16 bf16x2;
typedef __attribute__((ext_vector_type(8))) u16    ushort8v;
typedef __attribute__((ext_vector_type(2))) float  f32x2;
typedef __attribute__((ext_vector_type(4))) float  floatx4;

#define EMBED 1024
#define SEQ   2048
#define BATCH 4
#define NH    16
#define DKH   64
#define BHN   (BATCH*NH)              // 64
#define ZSTRIDE ((size_t)BHN*SEQ*DKH) // elements per Q/K/V plane

// ---- fp32 -> bf16 RTNE ----
__device__ __forceinline__ u16 f2bf(float f){
  union { float f; unsigned u; } v; v.f = f;
  unsigned r = (v.u + 0x7FFFu + ((v.u >> 16) & 1u)) >> 16;
  return (u16)r;
}
// packed pair via v_cvt_pk_bf16_f32
__device__ __forceinline__ u32 pk2(float a, float b){
  f32x2 v = {a, b};
  return __builtin_bit_cast(u32, __builtin_convertvector(v, bf16x2));
}

__device__ __forceinline__ bf16x8 ld_frag(const u16* p){
  return __builtin_bit_cast(bf16x8, *(const ushort8v*)p);
}

__device__ __forceinline__ floatx4 mfma16(bf16x8 a, bf16x8 b, floatx4 c){
  return __builtin_amdgcn_mfma_f32_16x16x32_bf16(a, b, c, 0, 0, 0);
}

// async global->LDS, 16B per lane; LDS dst must be uniform_base + lane*16
__device__ __forceinline__ void gl_lds16(const u16* g, u16* l){
  __builtin_amdgcn_global_load_lds((const __attribute__((address_space(1))) void*)g,
                                   (__attribute__((address_space(3))) void*)l,
                                   16, 0, 0);
}

// Counted-vmcnt barrier discipline (T4). GEMMs: two-barrier double-buffer.
// attn: TRIPLE buffer + ONE barrier per kt (waves may drift a full kt ->
// cross-pipe overlap between drifted waves; see attn comment).
#define CFENCE asm volatile("" ::: "memory")

// =================== fused cast kernel ===================
__global__ __launch_bounds__(256) void cvt_all(const float* __restrict__ x,
    const float* __restrict__ wq, const float* __restrict__ wk,
    const float* __restrict__ wv, const float* __restrict__ wo,
    u16* __restrict__ Xb, u16* __restrict__ Wqb, u16* __restrict__ Wkb,
    u16* __restrict__ Wvb, u16* __restrict__ Wob){
  int b = blockIdx.x;
  const float* src; u16* dst; int i;
  if (b < 8192){ src = x; dst = Xb; i = b*256 + threadIdx.x; }
  else {
    int k = (b - 8192) >> 10, r = (b - 8192) & 1023;
    src = (k==0) ? wq : (k==1) ? wk : (k==2) ? wv : wo;
    dst = (k==0) ? Wqb : (k==1) ? Wkb : (k==2) ? Wvb : Wob;
    i = r*256 + threadIdx.x;
  }
  float4 v = ((const float4*)src)[i];
  ushort4 o;
  o.x = f2bf(v.x); o.y = f2bf(v.y); o.z = f2bf(v.z); o.w = f2bf(v.w);
  ((ushort4*)dst)[i] = o;
}

// ============== fused QKV projection (R3-v1 + counted vmcnt) ===================
// grid (64, 8): x = m-tile (128 rows), y = n-tile (128 cols). Q,K,V share the
// A operand -> stage X ONCE per kt, 3 B tiles, 48 MFMA/wave/kt per barrier.
// LDS = 64 KB -> 2 blocks/CU. 8 DMA/thread/kt -> steady vmcnt(8).
#define QSCALE 0.1803368801111204f   // 0.125 * log2(e)
__global__ __launch_bounds__(256, 2) void gemm_qkv(const u16* __restrict__ X,
    const u16* __restrict__ Wq, const u16* __restrict__ Wk, const u16* __restrict__ Wv,
    u16* __restrict__ QKV){
  __shared__ __attribute__((aligned(16))) u16 As[2*128*32];      // 16 KB
  __shared__ __attribute__((aligned(16))) u16 Bs[3][2*128*32];   // 48 KB

  const int tid = threadIdx.x, lane = tid & 63, w = tid >> 6;
  const int lm = lane & 15, quad = lane >> 4;
  const int wm = (w & 1) * 64, wn = (w >> 1) * 64;
  const int m0 = blockIdx.x * 128, n0 = blockIdx.y * 128;
  const int row0 = tid >> 2, kc = tid & 3;

  const u16* A0 = X  + (size_t)(m0 + row0)*EMBED + kc*8;   // +64*EMBED for r=1
  const u16* B0[3] = {
    Wq + (size_t)(n0 + row0)*EMBED + kc*8,
    Wk + (size_t)(n0 + row0)*EMBED + kc*8,
    Wv + (size_t)(n0 + row0)*EMBED + kc*8 };

  floatx4 acc[3][4][4];
  #pragma unroll
  for (int z = 0; z < 3; ++z)
    #pragma unroll
    for (int mi = 0; mi < 4; ++mi)
      #pragma unroll
      for (int ni = 0; ni < 4; ++ni)
        acc[z][mi][ni] = (floatx4){0.f, 0.f, 0.f, 0.f};

  // prologue: stage kt=0 into buffer 0 (8 DMAs in flight)
  gl_lds16(A0,            As + tid*8);
  gl_lds16(A0 + 64*EMBED, As + (256 + tid)*8);
  #pragma unroll
  for (int z = 0; z < 3; ++z){
    gl_lds16(B0[z],            Bs[z] + tid*8);
    gl_lds16(B0[z] + 64*EMBED, Bs[z] + (256 + tid)*8);
  }

  for (int kt = 0; kt < EMBED/32; ++kt){
    const int cur = kt & 1;
    __builtin_amdgcn_s_barrier();          // B1: all waves done reading cur^1
    CFENCE;
    if (kt + 1 < EMBED/32){
      const int k0 = (kt + 1) * 32;
      gl_lds16(A0 + k0,            As + (cur^1)*4096 + tid*8);
      gl_lds16(A0 + 64*EMBED + k0, As + (cur^1)*4096 + (256 + tid)*8);
      #pragma unroll
      for (int z = 0; z < 3; ++z){
        gl_lds16(B0[z] + k0,            Bs[z] + (cur^1)*4096 + tid*8);
        gl_lds16(B0[z] + 64*EMBED + k0, Bs[z] + (cur^1)*4096 + (256 + tid)*8);
      }
      asm volatile("s_waitcnt vmcnt(8)" ::: "memory");   // cur landed, 8 in flight
    } else {
      asm volatile("s_waitcnt vmcnt(0)" ::: "memory");
    }
    __builtin_amdgcn_s_barrier();          // B2: cur landed block-wide
    CFENCE;
    const u16* Ac = As + cur*4096;
    bf16x8 af[4];
    #pragma unroll
    for (int mi = 0; mi < 4; ++mi)
      af[mi] = ld_frag(&Ac[(wm + mi*16 + lm)*32 + quad*8]);
    #pragma unroll
    for (int z = 0; z < 3; ++z){
      const u16* Bc = Bs[z] + cur*4096;
      bf16x8 bfz[4];
      #pragma unroll
      for (int ni = 0; ni < 4; ++ni)
        bfz[ni] = ld_frag(&Bc[(wn + ni*16 + lm)*32 + quad*8]);
      #pragma unroll
      for (int mi = 0; mi < 4; ++mi)
        #pragma unroll
        for (int ni = 0; ni < 4; ++ni)
          acc[z][mi][ni] = mfma16(af[mi], bfz[ni], acc[z][mi][ni]);
    }
  }

  // ---- epilogues: direct stores ----
  // z=0 (Q, scaled) and z=1 (K): [bh][s][d]
  #pragma unroll
  for (int z = 0; z < 2; ++z){
    const float scale = (z == 0) ? QSCALE : 1.0f;
    u16* outz = QKV + (size_t)z * ZSTRIDE;
    #pragma unroll
    for (int mi = 0; mi < 4; ++mi)
      #pragma unroll
      for (int ni = 0; ni < 4; ++ni)
        #pragma unroll
        for (int r = 0; r < 4; ++r){
          int m = m0 + wm + mi*16 + quad*4 + r;
          int n = n0 + wn + ni*16 + lm;
          int b = m >> 11, s = m & 2047, h = n >> 6, d = n & 63;
          outz[(((size_t)(b*NH + h))*SEQ + s)*DKH + d] = f2bf(acc[z][mi][ni][r] * scale);
        }
  }
  // z=2 (V): [bh][d][s], 4 consecutive s per thread -> uint2 store
  {
    u16* outz = QKV + (size_t)2 * ZSTRIDE;
    #pragma unroll
    for (int mi = 0; mi < 4; ++mi)
      #pragma unroll
      for (int ni = 0; ni < 4; ++ni){
        int mbase = m0 + wm + mi*16 + quad*4;
        int n = n0 + wn + ni*16 + lm;
        int b = mbase >> 11, sb = mbase & 2047;
        int h = n >> 6, d = n & 63;
        u16* dst = outz + (((size_t)(b*NH + h))*DKH + d)*SEQ + sb;
        uint2 pv;
        pv.x = pk2(acc[2][mi][ni][0], acc[2][mi][ni][1]);
        pv.y = pk2(acc[2][mi][ni][2], acc[2][mi][ni][3]);
        *reinterpret_cast<uint2*>(dst) = pv;
      }
  }
}

// Final: out = Attn * Wo^T, fp32 out [b*s][e]. grid (64, 8). BK=64,
// source-side XOR swizzle on staging, same XOR on read. Counted vmcnt(8).
__global__ __launch_bounds__(256) void gemm_out(const u16* __restrict__ A,
    const u16* __restrict__ W, float* __restrict__ C){
  __shared__ __attribute__((aligned(16))) u16 As[2*128*64];   // 32 KB
  __shared__ __attribute__((aligned(16))) u16 Bs[2*128*64];   // 32 KB
  const int tid = threadIdx.x, lane = tid & 63, w = tid >> 6;
  const int lm = lane & 15, quad = lane >> 4;
  const int wm = (w & 1) * 64, wn = (w >> 1) * 64;
  const int m0 = blockIdx.x * 128, n0 = blockIdx.y * 128;

  const int srow = tid >> 3;
  const int ssw  = ((tid & 7) ^ (srow & 7)) * 8;   // u16 col offset
  const u16* Ab = A + (size_t)(m0 + srow)*EMBED + ssw;
  const u16* Bb = W + (size_t)(n0 + srow)*EMBED + ssw;

  floatx4 acc[4][4];
  #pragma unroll
  for (int mi = 0; mi < 4; ++mi)
    #pragma unroll
    for (int ni = 0; ni < 4; ++ni)
      acc[mi][ni] = (floatx4){0.f, 0.f, 0.f, 0.f};

  #pragma unroll
  for (int j = 0; j < 4; ++j){
    gl_lds16(Ab + (size_t)j*32*EMBED, As + (j*256 + tid)*8);
    gl_lds16(Bb + (size_t)j*32*EMBED, Bs + (j*256 + tid)*8);
  }

  for (int kt = 0; kt < EMBED/64; ++kt){
    const int cur = kt & 1;
    __builtin_amdgcn_s_barrier();          // B1
    CFENCE;
    if (kt + 1 < EMBED/64){
      const int k0 = (kt + 1) * 64;
      #pragma unroll
      for (int j = 0; j < 4; ++j){
        gl_lds16(Ab + (size_t)j*32*EMBED + k0, As + (cur^1)*8192 + (j*256 + tid)*8);
        gl_lds16(Bb + (size_t)j*32*EMBED + k0, Bs + (cur^1)*8192 + (j*256 + tid)*8);
      }
      asm volatile("s_waitcnt vmcnt(8)" ::: "memory");
    } else {
      asm volatile("s_waitcnt vmcnt(0)" ::: "memory");
    }
    __builtin_amdgcn_s_barrier();          // B2
    CFENCE;
    const u16* Ac = As + cur*8192;
    const u16* Bc = Bs + cur*8192;
    #pragma unroll
    for (int kh = 0; kh < 2; ++kh){
      const int us = ((kh*4 + quad) ^ (lm & 7)) * 8;
      bf16x8 af[4], bf[4];
      #pragma unroll
      for (int mi = 0; mi < 4; ++mi)
        af[mi] = ld_frag(&Ac[(wm + mi*16 + lm)*64 + us]);
      #pragma unroll
      for (int ni = 0; ni < 4; ++ni)
        bf[ni] = ld_frag(&Bc[(wn + ni*16 + lm)*64 + us]);
      #pragma unroll
      for (int mi = 0; mi < 4; ++mi)
        #pragma unroll
        for (int ni = 0; ni < 4; ++ni)
          acc[mi][ni] = mfma16(af[mi], bf[ni], acc[mi][ni]);
    }
  }

  #pragma unroll
  for (int mi = 0; mi < 4; ++mi)
    #pragma unroll
    for (int ni = 0; ni < 4; ++ni)
      #pragma unroll
      for (int r = 0; r < 4; ++r){
        int m = m0 + wm + mi*16 + quad*4 + r;
        int n = n0 + wn + ni*16 + lm;
        C[(size_t)m*EMBED + n] = acc[mi][ni][r];
      }
}

// =================== fused attention (P stays in registers) ===================
// grid (64, 8): x = bh, y = q-block of 256 rows. 4 waves x 64 q (4 q-tiles).
// R9 diagnosis: MfmaUtil+VALUBusy+LDS ~= 100% of wall in BOTH R8/R9 configs —
// pipes never overlap. Cause: waves phase-locked by the per-kt barrier pair
// (all do QK-MFMA together, then exp2 together; m114 overlap needs phase
// diversity). Fix: TRIPLE-buffered K/V + ONE barrier per kt. DMA at kt
// targets buf[(kt+2)%3] whose readers (kt-1) all passed this kt-top barrier
// -> race-free with waves drifting up to a FULL kt: drifted waves feed
// different pipes simultaneously. Order: wait own vmcnt(4) (kt's loads are
// 2 kt old -> ~0 stall) -> s_barrier (block-wide "buf[kt] landed" + kt-1
// readers done) -> issue kt+2 -> compute. LDS 49.5 KB -> 2 blocks/CU.
#define KSS 520
#define NT  (SEQ/64)
__global__ __launch_bounds__(256, 2) void attn_kernel(const u16* __restrict__ QKV,
                                                      u16* __restrict__ Out){
  __shared__ __attribute__((aligned(16))) u16 Ks[3][8*KSS];   // 24.4 KB
  __shared__ __attribute__((aligned(16))) u16 Vs[3][64*64];   // 24.0 KB

  const int tid = threadIdx.x, lane = tid & 63, w = tid >> 6;
  const int lm = lane & 15, quad = lane >> 4;
  const int bh = blockIdx.x;
  const int q0 = blockIdx.y * 256;
  const u16* Qh = QKV + (size_t)bh * SEQ * DKH;
  const u16* Kh = QKV + ZSTRIDE + (size_t)bh * SEQ * DKH;
  const u16* Vh = QKV + 2*ZSTRIDE + (size_t)bh * DKH * SEQ;  // [d][s] plain

  const int sK = tid & 63, cK = tid >> 6;
  const int dV = tid >> 3, gV = tid & 7;
  const size_t vsrc0 = (size_t)dV * SEQ + ((gV ^ (dV & 7)) * 8);
  const size_t vsrc1 = vsrc0 + (size_t)32 * SEQ;

  // Q fragments: 4 q-tiles per wave (64 q rows), B-operand layout
  bf16x8 qf[4][2];
  #pragma unroll
  for (int qt = 0; qt < 4; ++qt)
    #pragma unroll
    for (int st = 0; st < 2; ++st)
      qf[qt][st] = ld_frag(Qh + (size_t)(q0 + w*64 + qt*16 + lm)*DKH + st*32 + quad*8);

  const uint4 ONESW = {0x3F803F80u, 0x3F803F80u, 0x3F803F80u, 0x3F803F80u};
  const bf16x8 ones8 = __builtin_bit_cast(bf16x8, ONESW);    // bf16 1.0 x8

  floatx4 o[4][4], lac[4];
  #pragma unroll
  for (int qt = 0; qt < 4; ++qt){
    lac[qt] = (floatx4){0.f, 0.f, 0.f, 0.f};
    #pragma unroll
    for (int dt = 0; dt < 4; ++dt) o[qt][dt] = (floatx4){0.f, 0.f, 0.f, 0.f};
  }

  // prologue: stage kt=0 -> buf0, kt=1 -> buf1 (8 DMAs in flight)
  #pragma unroll
  for (int p = 0; p < 2; ++p){
    const int nk0 = p * 64;
    gl_lds16(Kh + (size_t)(nk0 + sK)*DKH + cK*8,     Ks[p] + cK*KSS + sK*8);
    gl_lds16(Kh + (size_t)(nk0 + sK)*DKH + (cK+4)*8, Ks[p] + (cK+4)*KSS + sK*8);
    gl_lds16(Vh + vsrc0 + nk0,                       Vs[p] + tid*8);
    gl_lds16(Vh + vsrc1 + nk0,                       Vs[p] + 2048 + tid*8);
  }

  int cur = 0, wb = 2;                    // wb = (cur+2)%3
  for (int kt = 0; kt < NT; ++kt){
    if (kt + 1 < NT) asm volatile("s_waitcnt vmcnt(4)" ::: "memory");
    else             asm volatile("s_waitcnt vmcnt(0)" ::: "memory");
    __builtin_amdgcn_s_barrier();         // buf[cur] landed block-wide;
    CFENCE;                               // kt-1 readers all done -> wb free
    if (kt + 2 < NT){
      const int nk0 = (kt + 2) * 64;
      gl_lds16(Kh + (size_t)(nk0 + sK)*DKH + cK*8,     Ks[wb] + cK*KSS + sK*8);
      gl_lds16(Kh + (size_t)(nk0 + sK)*DKH + (cK+4)*8, Ks[wb] + (cK+4)*KSS + sK*8);
      gl_lds16(Vh + vsrc0 + nk0,                       Vs[wb] + tid*8);
      gl_lds16(Vh + vsrc1 + nk0,                       Vs[wb] + 2048 + tid*8);
    }
    const u16* Kc = Ks[cur];
    const u16* Vc = Vs[cur];

    #pragma unroll
    for (int u = 0; u < 2; ++u){           // pair of 16-key tiles = 32 keys
      uint2 e[4][2];                       // [qt][half]: exp'd P, 4 bf16 each
      #pragma unroll
      for (int half = 0; half < 2; ++half){
        const int t = u*2 + half;
        bf16x8 kf0 = ld_frag(&Kc[quad*KSS     + (t*16 + lm)*8]);
        bf16x8 kf1 = ld_frag(&Kc[(quad+4)*KSS + (t*16 + lm)*8]);
        #pragma unroll
        for (int qt = 0; qt < 4; ++qt){
          floatx4 s = (floatx4){0.f,0.f,0.f,0.f};
          s = mfma16(kf0, qf[qt][0], s);
          s = mfma16(kf1, qf[qt][1], s);
          e[qt][half].x = pk2(__builtin_amdgcn_exp2f(s[0]), __builtin_amdgcn_exp2f(s[1]));
          e[qt][half].y = pk2(__builtin_amdgcn_exp2f(s[2]), __builtin_amdgcn_exp2f(s[3]));
        }
      }
      // pack K=32 A-frags: slots 0-3 <- tile 2u, 4-7 <- tile 2u+1
      bf16x8 pf[4];
      #pragma unroll
      for (int qt = 0; qt < 4; ++qt){
        uint4 pp = {e[qt][0].x, e[qt][0].y, e[qt][1].x, e[qt][1].y};
        pf[qt] = __builtin_bit_cast(bf16x8, pp);
      }
      // l += P*1 (K=32)
      #pragma unroll
      for (int qt = 0; qt < 4; ++qt)
        lac[qt] = mfma16(pf[qt], ones8, lac[qt]);
      // O += P*V : B-frag = concat of the two tiles' b64 reads
      const int cg0 = (((u*4     + (quad >> 1)) ^ (lm & 7)) * 8) + (quad & 1) * 4;
      const int cg1 = (((u*4 + 2 + (quad >> 1)) ^ (lm & 7)) * 8) + (quad & 1) * 4;
      #pragma unroll
      for (int dt = 0; dt < 4; ++dt){
        uint2 vlo = *(const uint2*)(Vc + (dt*16 + lm)*64 + cg0);
        uint2 vhi = *(const uint2*)(Vc + (dt*16 + lm)*64 + cg1);
        uint4 vv = {vlo.x, vlo.y, vhi.x, vhi.y};
        bf16x8 vb = __builtin_bit_cast(bf16x8, vv);
        #pragma unroll
        for (int qt = 0; qt < 4; ++qt)
          o[qt][dt] = mfma16(pf[qt], vb, o[qt][dt]);
      }
    }
    cur = (cur == 2) ? 0 : cur + 1;
    wb  = (wb  == 2) ? 0 : wb  + 1;
  }

  const int bI = bh >> 4, h = bh & 15;
  #pragma unroll
  for (int qt = 0; qt < 4; ++qt){
    floatx4 inv;
    #pragma unroll
    for (int r = 0; r < 4; ++r) inv[r] = __builtin_amdgcn_rcpf(lac[qt][r]);
    #pragma unroll
    for (int dt = 0; dt < 4; ++dt)
      #pragma unroll
      for (int r = 0; r < 4; ++r){
        int s = q0 + w*64 + qt*16 + quad*4 + r;
        Out[((size_t)(bI*SEQ + s))*EMBED + h*DKH + dt*16 + lm] = f2bf(o[qt][dt][r] * inv[r]);
      }
  }
}

// =================== launch ===================
extern "C" void kernel_launch(void* const* d_in, const int* in_sizes, int n_in,
                              void* d_out, int out_size, void* d_ws, size_t ws_size,
                              hipStream_t stream){
  const float* x  = (const float*)d_in[0];
  const float* Wq = (const float*)d_in[1];
  const float* Wk = (const float*)d_in[2];
  const float* Wv = (const float*)d_in[3];
  const float* Wo = (const float*)d_in[4];
  float* out = (float*)d_out;

  char* ws = (char*)d_ws;
  u16* Xb  = (u16*)ws;                          // 16 MB
  u16* Wqb = (u16*)(ws + (size_t)16777216);     // 4 x 2 MB
  u16* Wkb = Wqb + 1048576;
  u16* Wvb = Wkb + 1048576;
  u16* Wob = Wvb + 1048576;
  u16* QKV = (u16*)(ws + (size_t)25165824);     // 3 x 16.78 MB
  u16* At  = (u16*)(ws + (size_t)75497472);     // 16 MB

  cvt_all<<<12288, 256, 0, stream>>>(x, Wq, Wk, Wv, Wo, Xb, Wqb, Wkb, Wvb, Wob);
  gemm_qkv<<<dim3(64, 8), 256, 0, stream>>>(Xb, Wqb, Wkb, Wvb, QKV);
  attn_kernel<<<dim3(64, 8), 256, 0, stream>>>(QKV, At);
  gemm_out<<<dim3(64, 8), 256, 0, stream>>>(At, Wob, out);
}